// Round 5
// baseline (149.604 us; speedup 1.0000x reference)
//
#include <hip/hip_runtime.h>
#include <math.h>

#pragma clang fp contract(off)

#define NIMG 16
#define NP   8732
#define NCLS 81
#define NFG  80
#define KTOP 1000
#define KPAD 1024
#define DETS 100
#define CAPMAX 166912          // >= 19*8732 (hard bound: <=19 softmax scores can exceed 0.05)
#define BASEBITS 0x3D000000u   // float bits of 0.03125, below 0.05 threshold; low 16 bits zero
#define CNT_STRIDE 64          // u32 units -> 256 B per image counter (own cacheline)
#define TILEB 137              // 64-prior tiles per image (137*64 >= 8732)
#define NB 640                 // hist bins: (sb-BASEBITS)>>16, clamp 639 (score<=1.0)

// ---- workspace layout (bytes) ----
#define OFF_BOXES  0u            // [NIMG][NP][4] f32 = 2,235,392
#define OFF_CNT    2235392u      // [NIMG] u32 @256B = 4,096
#define OFF_GHIST  2239488u      // [NIMG][640] u32 = 40,960
#define OFF_CSCORE 2280448u      // [NIMG][KPAD] f32
#define OFF_CLABEL 2345984u      // [NIMG][KPAD] i32
#define OFF_CBOX   2411520u      // [NIMG][KPAD] float4
#define OFF_COFFS  2673664u      // [NIMG][KPAD] float4
#define OFF_CAREA  2935808u      // [NIMG][KPAD] f32 (unused since R16; layout kept)
#define OFF_VALIDW 3001344u      // [NIMG][16] u64
#define OFF_MASK   3003392u      // [NIMG][16][KPAD] u64 column-major
#define OFF_CAND   5100544u      // [NIMG][cap] u64
#define MEMSET_LEN 45056u        // cnt + ghist (contiguous)

typedef unsigned long long u64;
typedef unsigned int u32;

#define AS_GLOBAL __attribute__((address_space(1)))
#define AS_LOCAL  __attribute__((address_space(3)))

// ============================================================ kernel 1
// 4 waves per 64-prior tile (verified R7-R10). Per-block LDS 640-bin score
// hist (R11), merged to global AFTER the emission loop (~14 nonzero bins/blk).
// R14: TILE-MAJOR grid (blockIdx = g*16 + b); per-wave atomic base on cnt[b]
// (order in cand[] is arbitrary; k_select sorts by full key).
__global__ __launch_bounds__(256, 6) void k_decode(
    const float* __restrict__ logits, const float* __restrict__ rel,
    const float* __restrict__ priors, const int* __restrict__ tsz,
    float* __restrict__ boxes_out, u64* __restrict__ cand,
    u32* __restrict__ cnt, u32* __restrict__ ghist, int cap)
{
#pragma clang fp contract(off)
    __shared__ __align__(16) float lx[64 * NCLS];   // 20,736 B flat [prior][class]
    __shared__ float pmx[4 * 64];
    __shared__ float psm[4 * 64];
    __shared__ u32 sok[64];
    __shared__ u32 lhist[NB];                        // 2,560 B
    int b  = blockIdx.x & 15;                        // image (XCD pin: b%8)
    int g  = blockIdx.x >> 4;                        // tile
    int p0 = g * 64;
    int t  = threadIdx.x;
    int lane = t & 63;
    int q = t >> 6;
    int npri = NP - p0; if (npri > 64) npri = 64;
    int words = npri * NCLS;

    // ---- async staging: chunks split across the 4 waves, one barrier ----
    const u32* s32 = (const u32*)(logits + ((size_t)b * NP + p0) * NCLS);
    u32* lxw = (u32*)lx;
    int full = words >> 8;                          // 1KB chunks (64 x 16 B)
    for (int k = q; k < full; k += 4)
        __builtin_amdgcn_global_load_lds(
            (AS_GLOBAL const u32*)(s32 + (k << 8) + (lane << 2)),
            (AS_LOCAL u32*)(lxw + (k << 8)), 16, 0, 0);
    int base = full << 8;
    int c4 = (words - base) >> 6;                   // 256B chunks (64 x 4 B)
    for (int k = q; k < c4; k += 4)
        __builtin_amdgcn_global_load_lds(
            (AS_GLOBAL const u32*)(s32 + base + (k << 6) + lane),
            (AS_LOCAL u32*)(lxw + base + (k << 6)), 4, 0, 0);
    int base2 = base + (c4 << 6);
    if (q == 0 && lane < words - base2) lxw[base2 + lane] = s32[base2 + lane];

    for (int i = t; i < NB; i += 256) lhist[i] = 0;  // overlaps DMA

    int p = p0 + lane;
    bool active = p < NP;

    // ---- box decode by wave 0 (independent of LDS; overlaps DMA) ----
    if (q == 0) {
        u32 ok = 0;
        if (active) {
            float4 pr = ((const float4*)priors)[p];
            float4 rl = ((const float4*)rel)[(size_t)b * NP + p];
            float W = (float)tsz[b * 2 + 1], H = (float)tsz[b * 2 + 0];
            float cx = pr.x + (rl.x * 0.1f) * pr.z;
            float cy = pr.y + (rl.y * 0.1f) * pr.w;
            float w_ = pr.z * expf(rl.z * 0.2f);
            float h_ = pr.w * expf(rl.w * 0.2f);
            float4 bx;
            bx.x = (cx - 0.5f * w_) * W; bx.y = (cy - 0.5f * h_) * H;
            bx.z = (cx + 0.5f * w_) * W; bx.w = (cy + 0.5f * h_) * H;
            ((float4*)boxes_out)[(size_t)b * NP + p] = bx;
            ok = ((bx.z - bx.x) >= 0.01f) && ((bx.w - bx.y) >= 0.01f);
        }
        sok[lane] = ok;
    }
    __syncthreads();                                 // #1: DMA drained + sok

    int tb = lane * NCLS;
    int nk = (q == 0) ? 21 : 20;                     // q==0 also owns c=80
    float x[21];
    #pragma unroll
    for (int k = 0; k < 21; ++k) {
        int c = q + 4 * k;
        x[k] = (k < nk) ? lx[tb + c] : -3.4e38f;
    }
    float pm = -3.4e38f;
    #pragma unroll
    for (int k = 0; k < 21; ++k) if (k < nk) pm = fmaxf(pm, x[k]);
    pmx[q * 64 + lane] = pm;
    __syncthreads();                                 // #2: partial max
    float m = fmaxf(fmaxf(pmx[lane], pmx[64 + lane]),
                    fmaxf(pmx[128 + lane], pmx[192 + lane]));

    float ps = 0.f;
    #pragma unroll
    for (int k = 0; k < 21; ++k) {
        if (k < nk) { x[k] = expf(x[k] - m); ps += x[k]; }
    }
    psm[q * 64 + lane] = ps;
    __syncthreads();                                 // #3: partial sum
    float s = (psm[lane] + psm[64 + lane]) + (psm[128 + lane] + psm[192 + lane]);

    float hi = 0.05000075f * s;
    float lo = 0.04999925f * s;
    u32 pass = 0, band = 0;
    u32 sizeok = sok[lane];
    if (active && sizeok) {
        #pragma unroll
        for (int k = 0; k < 21; ++k) {
            int c = q + 4 * k;
            if (k < nk && c >= 1) {
                bool pa = x[k] > hi;
                bool bd = (!pa) && (x[k] > lo);
                pass |= ((u32)pa) << k;
                band |= ((u32)bd) << k;
            }
        }
    }
    while (band) {
        int k = __builtin_ctz(band); band &= band - 1;
        int c = q + 4 * k;
        float e = expf(lx[tb + c] - m);
        if (e / s > 0.05f) pass |= 1u << k;
    }
    int cnt_t = __popc(pass);

    int pre = cnt_t;
    #pragma unroll
    for (int d = 1; d < 64; d <<= 1) {
        int o = __shfl_up(pre, d);
        if (lane >= d) pre += o;
    }
    // ---- per-wave base via one atomic (lane 63 holds wave total) ----
    u32 wbase = 0;
    if (lane == 63 && pre > 0)
        wbase = atomicAdd(cnt + b * CNT_STRIDE, (u32)pre);
    wbase = (u32)__shfl((int)wbase, 63);
    u32 pos = wbase + (u32)(pre - cnt_t);

    u64* cb = cand + (size_t)b * cap;
    u32 flatneg = 0xFFFFFFFFu - (u32)p * NFG;
    while (pass) {
        int k = __builtin_ctz(pass); pass &= pass - 1;
        int c = q + 4 * k;
        float e = expf(lx[tb + c] - m);
        float d = e / s;
        if ((int)pos < cap) {
            u32 sb = __float_as_uint(d);
            cb[pos] = ((u64)sb << 32) | (u64)(flatneg - (u32)(c - 1));
            u32 bin = (sb - BASEBITS) >> 16; if (bin > NB - 1) bin = NB - 1;
            atomicAdd(&lhist[bin], 1u);              // LDS, ~14 adds per block
        }
        ++pos;
    }
    __syncthreads();                                 // lhist complete
    u32* gh = ghist + b * NB;
    for (int i = t; i < NB; i += 256) {
        u32 v = lhist[i];
        if (v) atomicAdd(gh + i, v);                 // ~14 nonzero bins/block
    }
}

// ============================================================ suffix_find
// (rare fine-fallback path only): 8192-bin hierarchical suffix scan.
__device__ __forceinline__ void suffix_find(
    u32* hist, u32* wt, u32 K, int tid,
    volatile int* outI, volatile u32* outNext)
{
    int lane = tid & 63, w = tid >> 6;
    u32 v[8]; u32 tot = 0;
    #pragma unroll
    for (int k = 0; k < 8; ++k) { v[k] = hist[tid * 8 + k]; tot += v[k]; }
    u32 ws = tot;
    #pragma unroll
    for (int d = 1; d < 64; d <<= 1) {
        u32 o = __shfl_down(ws, d);
        if (lane + d < 64) ws += o;
    }
    if (lane == 0) wt[w] = ws;
    __syncthreads();
    u32 tail = 0;
    for (int w2 = w + 1; w2 < 16; ++w2) tail += wt[w2];
    u32 after = (ws - tot) + tail;
    u32 sufk[9];
    sufk[8] = after;
    #pragma unroll
    for (int k = 7; k >= 0; --k) sufk[k] = v[k] + sufk[k + 1];
    #pragma unroll
    for (int k = 0; k < 8; ++k) {
        if (sufk[k] >= K && sufk[k + 1] < K) {
            *outI = tid * 8 + k;
            *outNext = sufk[k + 1];
        }
    }
    __syncthreads();
}

// ============================================================ kernel 2
// FUSED select, ONE candidate pass (R11); pipelined float4 pass (R14);
// in-LDS fine refine -> 1024 sort common path (R15, -8us verified).
// R16: carea store dropped (k_iou recomputes bitwise-identically).
__global__ __launch_bounds__(1024) void k_select(
    const u64* __restrict__ cand, const u32* __restrict__ cnt,
    const u32* __restrict__ ghist, const float* __restrict__ boxes,
    float* __restrict__ cscore, int* __restrict__ clabel,
    float4* __restrict__ cbox, float4* __restrict__ coffs,
    u64* __restrict__ validw, int cap)
{
#pragma clang fp contract(off)
    __shared__ u32 h[NB];
    __shared__ __align__(16) u32 fh[8192];  // fine hists; reused as u64 buf2
    __shared__ u32 wt[16];
    __shared__ u64 buf[2048];
    __shared__ float red16[16];
    __shared__ int sh_c, sh_i2, sh_f;
    __shared__ u32 sh_S, sh_next, sh_d, sh_m, sh_S2, sh_m2;
    int b = blockIdx.x, t = threadIdx.x, lane = t & 63;
    u32 n = min(cnt[b * CNT_STRIDE], (u32)cap);
    const u64* cb = cand + (size_t)b * cap;
    const float4* cb4 = (const float4*)cb;          // cap even -> 16B aligned

    // ---- issue chunk 0 of the candidate pass NOW (overlaps hist scan) ----
    float4 cur[4];
    #pragma unroll
    for (int e = 0; e < 4; ++e) {
        u32 p2 = (u32)(e << 10) + (u32)t;           // pair index (keys 2p2,2p2+1)
        cur[e] = make_float4(0.f, 0.f, 0.f, 0.f);
        if ((p2 << 1) < n) cur[e] = cb4[p2];
    }

    for (int i = t; i < NB; i += 1024) h[i] = ghist[b * NB + i];
    if (t == 0) { sh_c = -2; sh_i2 = -2; sh_S = 0; sh_next = 0; sh_m = 0; }
    __syncthreads();
    // ---- wave-0 suffix scan of 640 bins (10/lane) ----
    if (t < 64) {
        u32 v[10]; u32 tot = 0;
        #pragma unroll
        for (int k = 0; k < 10; ++k) { v[k] = h[t * 10 + k]; tot += v[k]; }
        u32 ws = tot;
        #pragma unroll
        for (int d = 1; d < 64; d <<= 1) {
            u32 o = (u32)__shfl_down((int)ws, d);
            if (t + d < 64) ws += o;
        }
        u32 suf[11];
        suf[10] = ws - tot;                          // suffix after my bins
        #pragma unroll
        for (int k = 9; k >= 0; --k) suf[k] = v[k] + suf[k + 1];
        #pragma unroll
        for (int k = 0; k < 10; ++k) {
            if (suf[k] >= (u32)KTOP && suf[k + 1] < (u32)KTOP) {
                sh_c = t * 10 + k; sh_S = suf[k]; sh_next = suf[k + 1];
            }
        }
    }
    __syncthreads();
    int c = sh_c;
    u32 T = 0;
    bool common_path = false;
    if (c >= 0) {
        u32 Tc = BASEBITS + ((u32)c << 16);
        if (sh_S <= 2048u) {
            T = Tc;                                  // common path, no pass
            common_path = true;
        } else {                                     // rare: gran-8 refine (1 pass)
            u32 nhi = sh_next;
            for (int i = t; i < 8192; i += 1024) fh[i] = 0;
            __syncthreads();
            for (u32 i = (u32)t; i < n; i += 1024) {
                u32 sb = (u32)(cb[i] >> 32);
                if ((sb & 0xFFFF0000u) == Tc)
                    atomicAdd(&fh[(sb >> 3) & 0x1FFFu], 1u);
            }
            __syncthreads();
            suffix_find(fh, wt, (u32)KTOP - nhi, t, &sh_i2, &sh_d);
            T = (sh_i2 >= 0) ? (Tc + ((u32)sh_i2 << 3)) : Tc;
        }
    }
    // ---- the ONE candidate pass: compact survivors (>= T) into LDS buf ----
    // pipelined: process cur (in regs), issue next chunk first.
    for (u32 bs0 = 0; bs0 < n; bs0 += 8192) {
        u32 bs1 = bs0 + 8192;
        float4 nxt[4];
        if (bs1 < n) {
            #pragma unroll
            for (int e = 0; e < 4; ++e) {
                u32 p2 = (bs1 >> 1) + (u32)(e << 10) + (u32)t;
                nxt[e] = make_float4(0.f, 0.f, 0.f, 0.f);
                if ((p2 << 1) < n) nxt[e] = cb4[p2];
            }
        } else {
            #pragma unroll
            for (int e = 0; e < 4; ++e) nxt[e] = make_float4(0.f, 0.f, 0.f, 0.f);
        }
        #pragma unroll
        for (int e = 0; e < 4; ++e) {
            u32 gk = bs0 + (((u32)(e << 10) + (u32)t) << 1);   // first key idx
            u64 k0 = ((u64)__float_as_uint(cur[e].y) << 32) | (u64)__float_as_uint(cur[e].x);
            u64 k1 = ((u64)__float_as_uint(cur[e].w) << 32) | (u64)__float_as_uint(cur[e].z);
            bool pick0 = (gk < n)     && ((u32)(k0 >> 32) >= T);
            bool pick1 = (gk + 1 < n) && ((u32)(k1 >> 32) >= T);
            u64 bal0 = __ballot(pick0);
            u32 wb = 0;
            if (lane == 0 && bal0) wb = atomicAdd(&sh_m, (u32)__popcll(bal0));
            wb = (u32)__shfl((int)wb, 0);
            if (pick0) {
                u32 pos = wb + (u32)__popcll(bal0 & ((1ULL << lane) - 1ULL));
                if (pos < 2048) buf[pos] = k0;
            }
            u64 bal1 = __ballot(pick1);
            u32 wb1 = 0;
            if (lane == 0 && bal1) wb1 = atomicAdd(&sh_m, (u32)__popcll(bal1));
            wb1 = (u32)__shfl((int)wb1, 0);
            if (pick1) {
                u32 pos = wb1 + (u32)__popcll(bal1 & ((1ULL << lane) - 1ULL));
                if (pos < 2048) buf[pos] = k1;
            }
        }
        #pragma unroll
        for (int e = 0; e < 4; ++e) cur[e] = nxt[e];
    }
    __syncthreads();
    u32 m = min(sh_m, 2048u);
    for (int i = t; i < 2048; i += 1024) if ((u32)i >= m) buf[i] = 0ULL;
    __syncthreads();

    // ---- R15: choose sort width; in-LDS refine to reach 1024 ----
    int sortn = 2048;
    if (m <= 1024u) {
        sortn = 1024;
    } else if (common_path) {
        // T == Tc. nhi = sh_next keys lie strictly above coarse bin c; we
        // need K2 = KTOP - nhi more from the boundary bin. Refine the
        // threshold at gran-32 using only LDS-resident survivors.
        u32 nhi = sh_next;
        u32 K2 = (u32)KTOP - nhi;                   // >= 1
        u32 cbin = (BASEBITS >> 16) + (u32)c;
        for (int i = t; i < 2048; i += 1024) fh[i] = 0;
        if (t == 0) { sh_f = -1; sh_S2 = 0; sh_m2 = 0; }
        __syncthreads();
        u64 a0 = buf[t], a1 = buf[t + 1024];
        u32 s0 = (u32)(a0 >> 32), s1 = (u32)(a1 >> 32);
        if ((s0 >> 16) == cbin) atomicAdd(&fh[(s0 >> 5) & 0x7FFu], 1u);
        if ((s1 >> 16) == cbin) atomicAdd(&fh[(s1 >> 5) & 0x7FFu], 1u);
        __syncthreads();
        // suffix scan of 2048 fine bins (2/thread), mirrors suffix_find
        {
            int l2 = t & 63, w2 = t >> 6;
            u32 v0b = fh[t * 2], v1b = fh[t * 2 + 1];
            u32 tot = v0b + v1b;
            u32 ws = tot;
            #pragma unroll
            for (int d = 1; d < 64; d <<= 1) {
                u32 o = (u32)__shfl_down((int)ws, d);
                if (l2 + d < 64) ws += o;
            }
            if (l2 == 0) wt[w2] = ws;
            __syncthreads();
            u32 tail = 0;
            for (int ww = w2 + 1; ww < 16; ++ww) tail += wt[ww];
            u32 after = (ws - tot) + tail;           // suffix after my 2 bins
            u32 suf1 = v1b + after;                  // suffix from bin 2t+1
            u32 suf0 = v0b + suf1;                   // suffix from bin 2t
            if (suf0 >= K2 && suf1 < K2)  { sh_f = t * 2;     sh_S2 = suf0; }
            if (suf1 >= K2 && after < K2) { sh_f = t * 2 + 1; sh_S2 = suf1; }
        }
        __syncthreads();
        if (sh_f >= 0 && nhi + sh_S2 <= 1024u) {
            u32 T2 = (cbin << 16) | ((u32)sh_f << 5);
            u64* buf2 = (u64*)fh;                    // 16 KB scratch (hist dead)
            bool p0 = (s0 >= T2);                    // zeros have s=0 < T2
            bool p1 = (s1 >= T2);
            u64 bal = __ballot(p0);
            u32 wb = 0;
            if (lane == 0 && bal) wb = atomicAdd(&sh_m2, (u32)__popcll(bal));
            wb = (u32)__shfl((int)wb, 0);
            if (p0) buf2[wb + (u32)__popcll(bal & ((1ULL << lane) - 1ULL))] = a0;
            bal = __ballot(p1);
            wb = 0;
            if (lane == 0 && bal) wb = atomicAdd(&sh_m2, (u32)__popcll(bal));
            wb = (u32)__shfl((int)wb, 0);
            if (p1) buf2[wb + (u32)__popcll(bal & ((1ULL << lane) - 1ULL))] = a1;
            __syncthreads();
            u32 m2 = sh_m2;                          // == nhi + sh_S2 <= 1024
            buf[t] = (t < (int)m2) ? buf2[t] : 0ULL; // buf[1024..2048) unused now
            sortn = 1024;
            __syncthreads();
        }
    }

    if (sortn == 1024) {
        // ---- hybrid bitonic sort, 1024 elems, full-key desc ----
        for (int k = 2; k <= 1024; k <<= 1) {
            for (int j = k >> 1; j >= 64; j >>= 1) {
                int i = t;
                int ixj = i ^ j;
                if (ixj > i) {
                    u64 a = buf[i], bb = buf[ixj];
                    bool up = (i & k) == 0;
                    if (up ? (a < bb) : (a > bb)) { buf[i] = bb; buf[ixj] = a; }
                }
                __syncthreads();
            }
            u64 v0 = buf[t];
            bool up0 = (t & k) == 0;
            int js = ((k >> 1) < 32) ? (k >> 1) : 32;
            for (int j = js; j >= 1; j >>= 1) {
                u64 o0 = __shfl_xor(v0, j);
                bool lo0 = (t & j) == 0;
                v0 = (lo0 == up0) ? (v0 > o0 ? v0 : o0) : (v0 < o0 ? v0 : o0);
            }
            buf[t] = v0;
            __syncthreads();
        }
    } else {
        // ---- hybrid bitonic sort, 2048 elems, full-key desc (fallback) ----
        for (int k = 2; k <= 2048; k <<= 1) {
            for (int j = k >> 1; j >= 64; j >>= 1) {
                #pragma unroll
                for (int e = 0; e < 2; ++e) {
                    int i = t + e * 1024;
                    int ixj = i ^ j;
                    if (ixj > i) {
                        u64 a = buf[i], bb = buf[ixj];
                        bool up = (i & k) == 0;
                        if (up ? (a < bb) : (a > bb)) { buf[i] = bb; buf[ixj] = a; }
                    }
                }
                __syncthreads();
            }
            u64 v0 = buf[t], v1 = buf[t + 1024];
            bool up0 = (t & k) == 0;
            bool up1 = ((t + 1024) & k) == 0;
            int js = ((k >> 1) < 32) ? (k >> 1) : 32;
            for (int j = js; j >= 1; j >>= 1) {
                u64 o0 = __shfl_xor(v0, j);
                u64 o1 = __shfl_xor(v1, j);
                bool lo0 = (t & j) == 0;
                v0 = (lo0 == up0) ? (v0 > o0 ? v0 : o0) : (v0 < o0 ? v0 : o0);
                v1 = (lo0 == up1) ? (v1 > o1 ? v1 : o1) : (v1 < o1 ? v1 : o1);
            }
            buf[t] = v0; buf[t + 1024] = v1;
            __syncthreads();
        }
    }
    // ---- fused prep: t owns slot t of KPAD ----
    u64 key = (t < KTOP) ? buf[t] : 0ULL;
    float s = __uint_as_float((u32)(key >> 32));
    bool valid = s > 0.0f;
    u32 flat = valid ? (0xFFFFFFFFu - (u32)key) : 0u;
    int prior = (int)(flat / NFG);
    int cls = (int)(flat - (u32)prior * NFG) + 1;
    float4 bx = make_float4(0.f, 0.f, 0.f, 0.f);
    if (valid) bx = ((const float4*)boxes)[b * NP + prior];
    cscore[b * KPAD + t] = s;
    clabel[b * KPAD + t] = cls;
    cbox[b * KPAD + t] = bx;
    u64 vb = __ballot(valid);
    if (lane == 0) validw[b * 16 + (t >> 6)] = vb;
    float lm = valid ? fmaxf(fmaxf(bx.x, bx.y), fmaxf(bx.z, bx.w)) : 0.0f;
    lm = fmaxf(lm, 0.0f);
    #pragma unroll
    for (int d = 1; d < 64; d <<= 1) lm = fmaxf(lm, __shfl_xor(lm, d));
    if (lane == 0) red16[t >> 6] = lm;
    __syncthreads();
    float mc = red16[0];
    #pragma unroll
    for (int w = 1; w < 16; ++w) mc = fmaxf(mc, red16[w]);
    float off = (float)cls * (mc + 1.0f);
    float4 ob = valid ? make_float4(bx.x + off, bx.y + off, bx.z + off, bx.w + off)
                      : make_float4(0.f, 0.f, 0.f, 0.f);
    coffs[b * KPAD + t] = ob;
}

// ============================================================ kernel 3
// suppression bitmask, COLUMN-major: cmask[b][w][j] bit k = row (64w+k)
// suppresses column j. 256 blocks, tile-major grid (R14).
// R16: lower-triangle words (w > tile) are identically zero (j > r always
// false) and never read by k_nms -> skip compute AND store (halves VALU).
// Area recomputed at staging from coffs (bitwise = old carea: same expr,
// same inputs, contract off).
__global__ __launch_bounds__(1024) void k_iou(
    const float4* __restrict__ coffs, u64* __restrict__ cmask)
{
#pragma clang fp contract(off)
    __shared__ float4 bs[KPAD];
    __shared__ float as_[KPAD];
    int b = blockIdx.x & 15, tile = blockIdx.x >> 4;
    int t = threadIdx.x;
    float4 v = coffs[b * KPAD + t];
    bs[t] = v;
    as_[t] = (v.z - v.x) * (v.w - v.y);
    __syncthreads();
    int w = t >> 6;                                // row word
    if (w > tile) return;                          // all-zero word, never read
    int j = tile * 64 + (t & 63);                  // column (suppressee)
    float4 bj = bs[j];
    float aj = as_[j];
    int r0 = w * 64;
    u64 bits = 0;
    #pragma unroll 4
    for (int k = 0; k < 64; ++k) {
        int r = r0 + k;                            // wave-uniform row
        float4 br = bs[r];
        float ar = as_[r];
        float ltx = fmaxf(br.x, bj.x), lty = fmaxf(br.y, bj.y);
        float rbx = fminf(br.z, bj.z), rby = fminf(br.w, bj.w);
        float wx = fmaxf(rbx - ltx, 0.0f), wy = fmaxf(rby - lty, 0.0f);
        float inter = wx * wy;
        float denom = ((ar + aj) - inter) + 1e-9f;
        float iou = inter / denom;
        bool sup = (iou > 0.45f) && (j > r);
        bits |= ((u64)sup) << k;
    }
    cmask[((size_t)b * 16 + w) * KPAD + j] = bits;
}

// ============================================================ kernel 4
// NMS ballot fixpoint from LDS (R13); validw prefetch (R15).
// R16: triangular staging — fixpoint only reads word w at columns
// j >= 64w (w2 <= g), so stage 69.6 KB instead of 128 KB. Same LDS
// layout; unstaged regions never read.
__global__ __launch_bounds__(1024) void k_nms(
    const u64* __restrict__ cmask, const u64* __restrict__ validw,
    const float* __restrict__ cscore, const int* __restrict__ clabel,
    const float4* __restrict__ cbox, float* __restrict__ out)
{
    __shared__ __align__(16) u64 smask[16 * KPAD];   // 128 KB
    __shared__ u64 sk[16];
    __shared__ int pfx[17];
    __shared__ int slot[DETS];
    int b = blockIdx.x, t = threadIdx.x, lane = t & 63;

    // prefetch validw (wave 0 lanes 0..15, issued before staging)
    u64 vw_reg = 0;
    if (t < 16) vw_reg = validw[b * 16 + t];

    // ---- stage triangular mask to LDS: word w, columns >= 64w ----
    {
        const float4* cm4 = (const float4*)(cmask + (size_t)b * 16 * KPAD);
        float4* sm4 = (float4*)smask;
        #pragma unroll
        for (int w = 0; w < 16; ++w) {
            int base4 = (w * KPAD + w * 64) >> 1;    // float4 offset
            int cnt4 = (KPAD - w * 64) >> 1;         // 512 - 32w
            for (int i = t; i < cnt4; i += 1024)
                sm4[base4 + i] = cm4[base4 + i];
        }
    }
    __syncthreads();

    // ---- NMS ballot fixpoint on wave 0, reading LDS ----
    if (t < 64) {
        u64 kept[16];
        #pragma unroll
        for (int g = 0; g < 16; ++g) {
            u64 vg = (u64)__shfl((long long)vw_reg, g);
            bool rem = false;
            #pragma unroll
            for (int w2 = 0; w2 < 16; ++w2)
                if (w2 < g)
                    rem |= (kept[w2] & smask[w2 * KPAD + g * 64 + lane]) != 0ULL;
            u64 cg = smask[g * KPAD + g * 64 + lane];
            bool myv = ((vg >> lane) & 1ULL) && !rem;
            u64 K = __ballot(myv);
            for (;;) {
                u64 K2 = __ballot(myv && ((K & cg) == 0ULL));
                if (K2 == K) break;
                K = K2;
            }
            kept[g] = K;                           // wave-uniform
        }
        if (lane == 0) {
            int run = 0;
            #pragma unroll
            for (int l = 0; l < 16; ++l) {
                sk[l] = kept[l]; pfx[l] = run; run += __popcll(kept[l]);
            }
            pfx[16] = run;
        }
    }
    __syncthreads();
    if (t < 16) {
        int r = pfx[t];
        u64 wv = sk[t];
        while (wv && r < DETS) {
            int bit = __builtin_ctzll(wv);
            slot[r] = t * 64 + bit;
            ++r;
            wv &= wv - 1;
        }
    }
    __syncthreads();
    int total = min(pfx[16], DETS);
    if (t < DETS) {
        int r = t;
        float4 bx = make_float4(0.f, 0.f, 0.f, 0.f);
        float s = 0.0f;
        int lb = -1;
        if (r < total) {
            int cdx = slot[r];
            bx = cbox[b * KPAD + cdx];
            s = cscore[b * KPAD + cdx];
            lb = clabel[b * KPAD + cdx];
        }
        float* ob = out + ((size_t)b * DETS + r) * 4;
        ob[0] = bx.x; ob[1] = bx.y; ob[2] = bx.z; ob[3] = bx.w;
        out[NIMG * DETS * 4 + b * DETS + r] = s;
        out[NIMG * DETS * 4 + NIMG * DETS + b * DETS + r] = (float)lb;
    }
}

// ============================================================ launch
extern "C" void kernel_launch(void* const* d_in, const int* in_sizes, int n_in,
                              void* d_out, int out_size, void* d_ws, size_t ws_size,
                              hipStream_t stream) {
    const float* logits = (const float*)d_in[0];
    const float* rel    = (const float*)d_in[1];
    const float* priors = (const float*)d_in[2];
    const int*   tsz    = (const int*)d_in[3];
    float* out = (float*)d_out;
    char* ws = (char*)d_ws;

    float* boxes  = (float*)(ws + OFF_BOXES);
    u32*   cnt    = (u32*)(ws + OFF_CNT);
    u32*   ghist  = (u32*)(ws + OFF_GHIST);
    float* cscore = (float*)(ws + OFF_CSCORE);
    int*   clabel = (int*)(ws + OFF_CLABEL);
    float4* cbox  = (float4*)(ws + OFF_CBOX);
    float4* coffs = (float4*)(ws + OFF_COFFS);
    u64*   validw = (u64*)(ws + OFF_VALIDW);
    u64*   cmask  = (u64*)(ws + OFF_MASK);
    u64*   cand   = (u64*)(ws + OFF_CAND);

    long long avail = ((long long)ws_size - (long long)OFF_CAND) / (NIMG * 8);
    int cap = (int)(avail < CAPMAX ? (avail > 0 ? avail : 1) : CAPMAX);
    cap &= ~1;                                    // even -> 16B-aligned per-image base

    hipMemsetAsync(cnt, 0, MEMSET_LEN, stream);   // cnt + ghist
    k_decode<<<NIMG * TILEB, 256, 0, stream>>>(logits, rel, priors, tsz,
                                               boxes, cand, cnt, ghist, cap);
    k_select<<<NIMG, 1024, 0, stream>>>(cand, cnt, ghist, boxes, cscore, clabel,
                                        cbox, coffs, validw, cap);
    k_iou<<<NIMG * 16, 1024, 0, stream>>>(coffs, cmask);
    k_nms<<<NIMG, 1024, 0, stream>>>(cmask, validw, cscore, clabel, cbox, out);
}

// Round 6
// 145.946 us; speedup vs baseline: 1.0251x; 1.0251x over previous
//
#include <hip/hip_runtime.h>
#include <math.h>

#pragma clang fp contract(off)

#define NIMG 16
#define NP   8732
#define NCLS 81
#define NFG  80
#define KTOP 1000
#define KPAD 1024
#define DETS 100
#define CAPMAX 166912          // >= 19*8732 (hard bound: <=19 softmax scores can exceed 0.05)
#define BASEBITS 0x3D000000u   // float bits of 0.03125, below 0.05 threshold; low 16 bits zero
#define CNT_STRIDE 64          // u32 units -> 256 B per image counter (own cacheline)
#define TILEB 137              // 64-prior tiles per image (137*64 >= 8732)
#define NB 640                 // hist bins: (sb-BASEBITS)>>16, clamp 639 (score<=1.0)
#define IOUB 9                 // ceil(136 triangular wave-words / 16 waves)

// ---- workspace layout (bytes) ----
#define OFF_BOXES  0u            // [NIMG][NP][4] f32 = 2,235,392
#define OFF_CNT    2235392u      // [NIMG] u32 @256B = 4,096
#define OFF_GHIST  2239488u      // [NIMG][640] u32 = 40,960
#define OFF_CSCORE 2280448u      // [NIMG][KPAD] f32
#define OFF_CLABEL 2345984u      // [NIMG][KPAD] i32
#define OFF_CBOX   2411520u      // [NIMG][KPAD] float4
#define OFF_COFFS  2673664u      // [NIMG][KPAD] float4
#define OFF_CAREA  2935808u      // [NIMG][KPAD] f32 (unused since R16; layout kept)
#define OFF_VALIDW 3001344u      // [NIMG][16] u64
#define OFF_MASK   3003392u      // [NIMG][16][KPAD] u64 column-major
#define OFF_CAND   5100544u      // [NIMG][cap] u64
#define MEMSET_LEN 45056u        // cnt + ghist (contiguous)

typedef unsigned long long u64;
typedef unsigned int u32;

#define AS_GLOBAL __attribute__((address_space(1)))
#define AS_LOCAL  __attribute__((address_space(3)))

// ============================================================ kernel 1
// 4 waves per 64-prior tile (verified R7-R10). Per-block LDS 640-bin score
// hist (R11), merged to global AFTER the emission loop (~14 nonzero bins/blk).
// R14: TILE-MAJOR grid (blockIdx = g*16 + b); per-wave atomic base on cnt[b]
// (order in cand[] is arbitrary; k_select sorts by full key).
__global__ __launch_bounds__(256, 6) void k_decode(
    const float* __restrict__ logits, const float* __restrict__ rel,
    const float* __restrict__ priors, const int* __restrict__ tsz,
    float* __restrict__ boxes_out, u64* __restrict__ cand,
    u32* __restrict__ cnt, u32* __restrict__ ghist, int cap)
{
#pragma clang fp contract(off)
    __shared__ __align__(16) float lx[64 * NCLS];   // 20,736 B flat [prior][class]
    __shared__ float pmx[4 * 64];
    __shared__ float psm[4 * 64];
    __shared__ u32 sok[64];
    __shared__ u32 lhist[NB];                        // 2,560 B
    int b  = blockIdx.x & 15;                        // image (XCD pin: b%8)
    int g  = blockIdx.x >> 4;                        // tile
    int p0 = g * 64;
    int t  = threadIdx.x;
    int lane = t & 63;
    int q = t >> 6;
    int npri = NP - p0; if (npri > 64) npri = 64;
    int words = npri * NCLS;

    // ---- async staging: chunks split across the 4 waves, one barrier ----
    const u32* s32 = (const u32*)(logits + ((size_t)b * NP + p0) * NCLS);
    u32* lxw = (u32*)lx;
    int full = words >> 8;                          // 1KB chunks (64 x 16 B)
    for (int k = q; k < full; k += 4)
        __builtin_amdgcn_global_load_lds(
            (AS_GLOBAL const u32*)(s32 + (k << 8) + (lane << 2)),
            (AS_LOCAL u32*)(lxw + (k << 8)), 16, 0, 0);
    int base = full << 8;
    int c4 = (words - base) >> 6;                   // 256B chunks (64 x 4 B)
    for (int k = q; k < c4; k += 4)
        __builtin_amdgcn_global_load_lds(
            (AS_GLOBAL const u32*)(s32 + base + (k << 6) + lane),
            (AS_LOCAL u32*)(lxw + base + (k << 6)), 4, 0, 0);
    int base2 = base + (c4 << 6);
    if (q == 0 && lane < words - base2) lxw[base2 + lane] = s32[base2 + lane];

    for (int i = t; i < NB; i += 256) lhist[i] = 0;  // overlaps DMA

    int p = p0 + lane;
    bool active = p < NP;

    // ---- box decode by wave 0 (independent of LDS; overlaps DMA) ----
    if (q == 0) {
        u32 ok = 0;
        if (active) {
            float4 pr = ((const float4*)priors)[p];
            float4 rl = ((const float4*)rel)[(size_t)b * NP + p];
            float W = (float)tsz[b * 2 + 1], H = (float)tsz[b * 2 + 0];
            float cx = pr.x + (rl.x * 0.1f) * pr.z;
            float cy = pr.y + (rl.y * 0.1f) * pr.w;
            float w_ = pr.z * expf(rl.z * 0.2f);
            float h_ = pr.w * expf(rl.w * 0.2f);
            float4 bx;
            bx.x = (cx - 0.5f * w_) * W; bx.y = (cy - 0.5f * h_) * H;
            bx.z = (cx + 0.5f * w_) * W; bx.w = (cy + 0.5f * h_) * H;
            ((float4*)boxes_out)[(size_t)b * NP + p] = bx;
            ok = ((bx.z - bx.x) >= 0.01f) && ((bx.w - bx.y) >= 0.01f);
        }
        sok[lane] = ok;
    }
    __syncthreads();                                 // #1: DMA drained + sok

    int tb = lane * NCLS;
    int nk = (q == 0) ? 21 : 20;                     // q==0 also owns c=80
    float x[21];
    #pragma unroll
    for (int k = 0; k < 21; ++k) {
        int c = q + 4 * k;
        x[k] = (k < nk) ? lx[tb + c] : -3.4e38f;
    }
    float pm = -3.4e38f;
    #pragma unroll
    for (int k = 0; k < 21; ++k) if (k < nk) pm = fmaxf(pm, x[k]);
    pmx[q * 64 + lane] = pm;
    __syncthreads();                                 // #2: partial max
    float m = fmaxf(fmaxf(pmx[lane], pmx[64 + lane]),
                    fmaxf(pmx[128 + lane], pmx[192 + lane]));

    float ps = 0.f;
    #pragma unroll
    for (int k = 0; k < 21; ++k) {
        if (k < nk) { x[k] = expf(x[k] - m); ps += x[k]; }
    }
    psm[q * 64 + lane] = ps;
    __syncthreads();                                 // #3: partial sum
    float s = (psm[lane] + psm[64 + lane]) + (psm[128 + lane] + psm[192 + lane]);

    float hi = 0.05000075f * s;
    float lo = 0.04999925f * s;
    u32 pass = 0, band = 0;
    u32 sizeok = sok[lane];
    if (active && sizeok) {
        #pragma unroll
        for (int k = 0; k < 21; ++k) {
            int c = q + 4 * k;
            if (k < nk && c >= 1) {
                bool pa = x[k] > hi;
                bool bd = (!pa) && (x[k] > lo);
                pass |= ((u32)pa) << k;
                band |= ((u32)bd) << k;
            }
        }
    }
    while (band) {
        int k = __builtin_ctz(band); band &= band - 1;
        int c = q + 4 * k;
        float e = expf(lx[tb + c] - m);
        if (e / s > 0.05f) pass |= 1u << k;
    }
    int cnt_t = __popc(pass);

    int pre = cnt_t;
    #pragma unroll
    for (int d = 1; d < 64; d <<= 1) {
        int o = __shfl_up(pre, d);
        if (lane >= d) pre += o;
    }
    // ---- per-wave base via one atomic (lane 63 holds wave total) ----
    u32 wbase = 0;
    if (lane == 63 && pre > 0)
        wbase = atomicAdd(cnt + b * CNT_STRIDE, (u32)pre);
    wbase = (u32)__shfl((int)wbase, 63);
    u32 pos = wbase + (u32)(pre - cnt_t);

    u64* cb = cand + (size_t)b * cap;
    u32 flatneg = 0xFFFFFFFFu - (u32)p * NFG;
    while (pass) {
        int k = __builtin_ctz(pass); pass &= pass - 1;
        int c = q + 4 * k;
        float e = expf(lx[tb + c] - m);
        float d = e / s;
        if ((int)pos < cap) {
            u32 sb = __float_as_uint(d);
            cb[pos] = ((u64)sb << 32) | (u64)(flatneg - (u32)(c - 1));
            u32 bin = (sb - BASEBITS) >> 16; if (bin > NB - 1) bin = NB - 1;
            atomicAdd(&lhist[bin], 1u);              // LDS, ~14 adds per block
        }
        ++pos;
    }
    __syncthreads();                                 // lhist complete
    u32* gh = ghist + b * NB;
    for (int i = t; i < NB; i += 256) {
        u32 v = lhist[i];
        if (v) atomicAdd(gh + i, v);                 // ~14 nonzero bins/block
    }
}

// ============================================================ suffix_find
// (rare fine-fallback path only): 8192-bin hierarchical suffix scan.
__device__ __forceinline__ void suffix_find(
    u32* hist, u32* wt, u32 K, int tid,
    volatile int* outI, volatile u32* outNext)
{
    int lane = tid & 63, w = tid >> 6;
    u32 v[8]; u32 tot = 0;
    #pragma unroll
    for (int k = 0; k < 8; ++k) { v[k] = hist[tid * 8 + k]; tot += v[k]; }
    u32 ws = tot;
    #pragma unroll
    for (int d = 1; d < 64; d <<= 1) {
        u32 o = __shfl_down(ws, d);
        if (lane + d < 64) ws += o;
    }
    if (lane == 0) wt[w] = ws;
    __syncthreads();
    u32 tail = 0;
    for (int w2 = w + 1; w2 < 16; ++w2) tail += wt[w2];
    u32 after = (ws - tot) + tail;
    u32 sufk[9];
    sufk[8] = after;
    #pragma unroll
    for (int k = 7; k >= 0; --k) sufk[k] = v[k] + sufk[k + 1];
    #pragma unroll
    for (int k = 0; k < 8; ++k) {
        if (sufk[k] >= K && sufk[k + 1] < K) {
            *outI = tid * 8 + k;
            *outNext = sufk[k + 1];
        }
    }
    __syncthreads();
}

// ============================================================ kernel 2
// FUSED select, ONE candidate pass (R11); pipelined float4 pass (R14);
// in-LDS fine refine -> 1024 sort common path (R15, -8us verified).
// carea store dropped (R16; k_iou recomputes bitwise-identically).
__global__ __launch_bounds__(1024) void k_select(
    const u64* __restrict__ cand, const u32* __restrict__ cnt,
    const u32* __restrict__ ghist, const float* __restrict__ boxes,
    float* __restrict__ cscore, int* __restrict__ clabel,
    float4* __restrict__ cbox, float4* __restrict__ coffs,
    u64* __restrict__ validw, int cap)
{
#pragma clang fp contract(off)
    __shared__ u32 h[NB];
    __shared__ __align__(16) u32 fh[8192];  // fine hists; reused as u64 buf2
    __shared__ u32 wt[16];
    __shared__ u64 buf[2048];
    __shared__ float red16[16];
    __shared__ int sh_c, sh_i2, sh_f;
    __shared__ u32 sh_S, sh_next, sh_d, sh_m, sh_S2, sh_m2;
    int b = blockIdx.x, t = threadIdx.x, lane = t & 63;
    u32 n = min(cnt[b * CNT_STRIDE], (u32)cap);
    const u64* cb = cand + (size_t)b * cap;
    const float4* cb4 = (const float4*)cb;          // cap even -> 16B aligned

    // ---- issue chunk 0 of the candidate pass NOW (overlaps hist scan) ----
    float4 cur[4];
    #pragma unroll
    for (int e = 0; e < 4; ++e) {
        u32 p2 = (u32)(e << 10) + (u32)t;           // pair index (keys 2p2,2p2+1)
        cur[e] = make_float4(0.f, 0.f, 0.f, 0.f);
        if ((p2 << 1) < n) cur[e] = cb4[p2];
    }

    for (int i = t; i < NB; i += 1024) h[i] = ghist[b * NB + i];
    if (t == 0) { sh_c = -2; sh_i2 = -2; sh_S = 0; sh_next = 0; sh_m = 0; }
    __syncthreads();
    // ---- wave-0 suffix scan of 640 bins (10/lane) ----
    if (t < 64) {
        u32 v[10]; u32 tot = 0;
        #pragma unroll
        for (int k = 0; k < 10; ++k) { v[k] = h[t * 10 + k]; tot += v[k]; }
        u32 ws = tot;
        #pragma unroll
        for (int d = 1; d < 64; d <<= 1) {
            u32 o = (u32)__shfl_down((int)ws, d);
            if (t + d < 64) ws += o;
        }
        u32 suf[11];
        suf[10] = ws - tot;                          // suffix after my bins
        #pragma unroll
        for (int k = 9; k >= 0; --k) suf[k] = v[k] + suf[k + 1];
        #pragma unroll
        for (int k = 0; k < 10; ++k) {
            if (suf[k] >= (u32)KTOP && suf[k + 1] < (u32)KTOP) {
                sh_c = t * 10 + k; sh_S = suf[k]; sh_next = suf[k + 1];
            }
        }
    }
    __syncthreads();
    int c = sh_c;
    u32 T = 0;
    bool common_path = false;
    if (c >= 0) {
        u32 Tc = BASEBITS + ((u32)c << 16);
        if (sh_S <= 2048u) {
            T = Tc;                                  // common path, no pass
            common_path = true;
        } else {                                     // rare: gran-8 refine (1 pass)
            u32 nhi = sh_next;
            for (int i = t; i < 8192; i += 1024) fh[i] = 0;
            __syncthreads();
            for (u32 i = (u32)t; i < n; i += 1024) {
                u32 sb = (u32)(cb[i] >> 32);
                if ((sb & 0xFFFF0000u) == Tc)
                    atomicAdd(&fh[(sb >> 3) & 0x1FFFu], 1u);
            }
            __syncthreads();
            suffix_find(fh, wt, (u32)KTOP - nhi, t, &sh_i2, &sh_d);
            T = (sh_i2 >= 0) ? (Tc + ((u32)sh_i2 << 3)) : Tc;
        }
    }
    // ---- the ONE candidate pass: compact survivors (>= T) into LDS buf ----
    // pipelined: process cur (in regs), issue next chunk first.
    for (u32 bs0 = 0; bs0 < n; bs0 += 8192) {
        u32 bs1 = bs0 + 8192;
        float4 nxt[4];
        if (bs1 < n) {
            #pragma unroll
            for (int e = 0; e < 4; ++e) {
                u32 p2 = (bs1 >> 1) + (u32)(e << 10) + (u32)t;
                nxt[e] = make_float4(0.f, 0.f, 0.f, 0.f);
                if ((p2 << 1) < n) nxt[e] = cb4[p2];
            }
        } else {
            #pragma unroll
            for (int e = 0; e < 4; ++e) nxt[e] = make_float4(0.f, 0.f, 0.f, 0.f);
        }
        #pragma unroll
        for (int e = 0; e < 4; ++e) {
            u32 gk = bs0 + (((u32)(e << 10) + (u32)t) << 1);   // first key idx
            u64 k0 = ((u64)__float_as_uint(cur[e].y) << 32) | (u64)__float_as_uint(cur[e].x);
            u64 k1 = ((u64)__float_as_uint(cur[e].w) << 32) | (u64)__float_as_uint(cur[e].z);
            bool pick0 = (gk < n)     && ((u32)(k0 >> 32) >= T);
            bool pick1 = (gk + 1 < n) && ((u32)(k1 >> 32) >= T);
            u64 bal0 = __ballot(pick0);
            u32 wb = 0;
            if (lane == 0 && bal0) wb = atomicAdd(&sh_m, (u32)__popcll(bal0));
            wb = (u32)__shfl((int)wb, 0);
            if (pick0) {
                u32 pos = wb + (u32)__popcll(bal0 & ((1ULL << lane) - 1ULL));
                if (pos < 2048) buf[pos] = k0;
            }
            u64 bal1 = __ballot(pick1);
            u32 wb1 = 0;
            if (lane == 0 && bal1) wb1 = atomicAdd(&sh_m, (u32)__popcll(bal1));
            wb1 = (u32)__shfl((int)wb1, 0);
            if (pick1) {
                u32 pos = wb1 + (u32)__popcll(bal1 & ((1ULL << lane) - 1ULL));
                if (pos < 2048) buf[pos] = k1;
            }
        }
        #pragma unroll
        for (int e = 0; e < 4; ++e) cur[e] = nxt[e];
    }
    __syncthreads();
    u32 m = min(sh_m, 2048u);
    for (int i = t; i < 2048; i += 1024) if ((u32)i >= m) buf[i] = 0ULL;
    __syncthreads();

    // ---- R15: choose sort width; in-LDS refine to reach 1024 ----
    int sortn = 2048;
    if (m <= 1024u) {
        sortn = 1024;
    } else if (common_path) {
        // T == Tc. nhi = sh_next keys lie strictly above coarse bin c; we
        // need K2 = KTOP - nhi more from the boundary bin. Refine the
        // threshold at gran-32 using only LDS-resident survivors.
        u32 nhi = sh_next;
        u32 K2 = (u32)KTOP - nhi;                   // >= 1
        u32 cbin = (BASEBITS >> 16) + (u32)c;
        for (int i = t; i < 2048; i += 1024) fh[i] = 0;
        if (t == 0) { sh_f = -1; sh_S2 = 0; sh_m2 = 0; }
        __syncthreads();
        u64 a0 = buf[t], a1 = buf[t + 1024];
        u32 s0 = (u32)(a0 >> 32), s1 = (u32)(a1 >> 32);
        if ((s0 >> 16) == cbin) atomicAdd(&fh[(s0 >> 5) & 0x7FFu], 1u);
        if ((s1 >> 16) == cbin) atomicAdd(&fh[(s1 >> 5) & 0x7FFu], 1u);
        __syncthreads();
        // suffix scan of 2048 fine bins (2/thread), mirrors suffix_find
        {
            int l2 = t & 63, w2 = t >> 6;
            u32 v0b = fh[t * 2], v1b = fh[t * 2 + 1];
            u32 tot = v0b + v1b;
            u32 ws = tot;
            #pragma unroll
            for (int d = 1; d < 64; d <<= 1) {
                u32 o = (u32)__shfl_down((int)ws, d);
                if (l2 + d < 64) ws += o;
            }
            if (l2 == 0) wt[w2] = ws;
            __syncthreads();
            u32 tail = 0;
            for (int ww = w2 + 1; ww < 16; ++ww) tail += wt[ww];
            u32 after = (ws - tot) + tail;           // suffix after my 2 bins
            u32 suf1 = v1b + after;                  // suffix from bin 2t+1
            u32 suf0 = v0b + suf1;                   // suffix from bin 2t
            if (suf0 >= K2 && suf1 < K2)  { sh_f = t * 2;     sh_S2 = suf0; }
            if (suf1 >= K2 && after < K2) { sh_f = t * 2 + 1; sh_S2 = suf1; }
        }
        __syncthreads();
        if (sh_f >= 0 && nhi + sh_S2 <= 1024u) {
            u32 T2 = (cbin << 16) | ((u32)sh_f << 5);
            u64* buf2 = (u64*)fh;                    // 16 KB scratch (hist dead)
            bool p0 = (s0 >= T2);                    // zeros have s=0 < T2
            bool p1 = (s1 >= T2);
            u64 bal = __ballot(p0);
            u32 wb = 0;
            if (lane == 0 && bal) wb = atomicAdd(&sh_m2, (u32)__popcll(bal));
            wb = (u32)__shfl((int)wb, 0);
            if (p0) buf2[wb + (u32)__popcll(bal & ((1ULL << lane) - 1ULL))] = a0;
            bal = __ballot(p1);
            wb = 0;
            if (lane == 0 && bal) wb = atomicAdd(&sh_m2, (u32)__popcll(bal));
            wb = (u32)__shfl((int)wb, 0);
            if (p1) buf2[wb + (u32)__popcll(bal & ((1ULL << lane) - 1ULL))] = a1;
            __syncthreads();
            u32 m2 = sh_m2;                          // == nhi + sh_S2 <= 1024
            buf[t] = (t < (int)m2) ? buf2[t] : 0ULL; // buf[1024..2048) unused now
            sortn = 1024;
            __syncthreads();
        }
    }

    if (sortn == 1024) {
        // ---- hybrid bitonic sort, 1024 elems, full-key desc ----
        for (int k = 2; k <= 1024; k <<= 1) {
            for (int j = k >> 1; j >= 64; j >>= 1) {
                int i = t;
                int ixj = i ^ j;
                if (ixj > i) {
                    u64 a = buf[i], bb = buf[ixj];
                    bool up = (i & k) == 0;
                    if (up ? (a < bb) : (a > bb)) { buf[i] = bb; buf[ixj] = a; }
                }
                __syncthreads();
            }
            u64 v0 = buf[t];
            bool up0 = (t & k) == 0;
            int js = ((k >> 1) < 32) ? (k >> 1) : 32;
            for (int j = js; j >= 1; j >>= 1) {
                u64 o0 = __shfl_xor(v0, j);
                bool lo0 = (t & j) == 0;
                v0 = (lo0 == up0) ? (v0 > o0 ? v0 : o0) : (v0 < o0 ? v0 : o0);
            }
            buf[t] = v0;
            __syncthreads();
        }
    } else {
        // ---- hybrid bitonic sort, 2048 elems, full-key desc (fallback) ----
        for (int k = 2; k <= 2048; k <<= 1) {
            for (int j = k >> 1; j >= 64; j >>= 1) {
                #pragma unroll
                for (int e = 0; e < 2; ++e) {
                    int i = t + e * 1024;
                    int ixj = i ^ j;
                    if (ixj > i) {
                        u64 a = buf[i], bb = buf[ixj];
                        bool up = (i & k) == 0;
                        if (up ? (a < bb) : (a > bb)) { buf[i] = bb; buf[ixj] = a; }
                    }
                }
                __syncthreads();
            }
            u64 v0 = buf[t], v1 = buf[t + 1024];
            bool up0 = (t & k) == 0;
            bool up1 = ((t + 1024) & k) == 0;
            int js = ((k >> 1) < 32) ? (k >> 1) : 32;
            for (int j = js; j >= 1; j >>= 1) {
                u64 o0 = __shfl_xor(v0, j);
                u64 o1 = __shfl_xor(v1, j);
                bool lo0 = (t & j) == 0;
                v0 = (lo0 == up0) ? (v0 > o0 ? v0 : o0) : (v0 < o0 ? v0 : o0);
                v1 = (lo0 == up1) ? (v1 > o1 ? v1 : o1) : (v1 < o1 ? v1 : o1);
            }
            buf[t] = v0; buf[t + 1024] = v1;
            __syncthreads();
        }
    }
    // ---- fused prep: t owns slot t of KPAD ----
    u64 key = (t < KTOP) ? buf[t] : 0ULL;
    float s = __uint_as_float((u32)(key >> 32));
    bool valid = s > 0.0f;
    u32 flat = valid ? (0xFFFFFFFFu - (u32)key) : 0u;
    int prior = (int)(flat / NFG);
    int cls = (int)(flat - (u32)prior * NFG) + 1;
    float4 bx = make_float4(0.f, 0.f, 0.f, 0.f);
    if (valid) bx = ((const float4*)boxes)[b * NP + prior];
    cscore[b * KPAD + t] = s;
    clabel[b * KPAD + t] = cls;
    cbox[b * KPAD + t] = bx;
    u64 vb = __ballot(valid);
    if (lane == 0) validw[b * 16 + (t >> 6)] = vb;
    float lm = valid ? fmaxf(fmaxf(bx.x, bx.y), fmaxf(bx.z, bx.w)) : 0.0f;
    lm = fmaxf(lm, 0.0f);
    #pragma unroll
    for (int d = 1; d < 64; d <<= 1) lm = fmaxf(lm, __shfl_xor(lm, d));
    if (lane == 0) red16[t >> 6] = lm;
    __syncthreads();
    float mc = red16[0];
    #pragma unroll
    for (int w = 1; w < 16; ++w) mc = fmaxf(mc, red16[w]);
    float off = (float)cls * (mc + 1.0f);
    float4 ob = valid ? make_float4(bx.x + off, bx.y + off, bx.z + off, bx.w + off)
                      : make_float4(0.f, 0.f, 0.f, 0.f);
    coffs[b * KPAD + t] = ob;
}

// ============================================================ kernel 3
// suppression bitmask, COLUMN-major: cmask[b][w][j] bit k = row (64w+k)
// suppresses column j. R17: FLAT TRIANGULAR grid — only the 136 live
// (tile,w) wave-words per image (w <= tile; lower triangle is identically
// zero and never read), packed 16 waves/block -> NIMG x 9 fully-active
// blocks instead of 256 half-empty ones. Every wave computes exactly one
// word. Same bits, same stores. Area recomputed at staging (bitwise =
// old carea: same expr, same inputs, contract off).
__global__ __launch_bounds__(1024) void k_iou(
    const float4* __restrict__ coffs, u64* __restrict__ cmask)
{
#pragma clang fp contract(off)
    __shared__ float4 bs[KPAD];
    __shared__ float as_[KPAD];
    int b = blockIdx.x & 15, blk = blockIdx.x >> 4;
    int t = threadIdx.x;
    float4 v = coffs[b * KPAD + t];
    bs[t] = v;
    as_[t] = (v.z - v.x) * (v.w - v.y);
    __syncthreads();
    int f = blk * 16 + (t >> 6);                   // flat triangular word id
    if (f >= 136) return;                          // tail waves (no barrier after)
    int tile = 0;                                  // invert f = T(tile)+w
    #pragma unroll
    for (int x = 1; x < 16; ++x) if (x * (x + 1) / 2 <= f) tile = x;
    int w = f - tile * (tile + 1) / 2;             // w <= tile by construction
    int j = tile * 64 + (t & 63);                  // column (suppressee)
    float4 bj = bs[j];
    float aj = as_[j];
    int r0 = w * 64;
    u64 bits = 0;
    #pragma unroll 4
    for (int k = 0; k < 64; ++k) {
        int r = r0 + k;                            // wave-uniform row
        float4 br = bs[r];
        float ar = as_[r];
        float ltx = fmaxf(br.x, bj.x), lty = fmaxf(br.y, bj.y);
        float rbx = fminf(br.z, bj.z), rby = fminf(br.w, bj.w);
        float wx = fmaxf(rbx - ltx, 0.0f), wy = fmaxf(rby - lty, 0.0f);
        float inter = wx * wy;
        float denom = ((ar + aj) - inter) + 1e-9f;
        float iou = inter / denom;
        bool sup = (iou > 0.45f) && (j > r);
        bits |= ((u64)sup) << k;
    }
    cmask[((size_t)b * 16 + w) * KPAD + j] = bits;
}

// ============================================================ kernel 4
// NMS ballot fixpoint from LDS (R13); validw prefetch (R15).
// R17: staging reverted to the R15-proven full 128 KB 8x-unrolled form
// (R16's triangular loop regressed: <=512/1024 active threads per round +
// branches beat the 58 KB byte saving). Lower-triangle words now hold
// garbage (k_iou skips them) — harmless: the fixpoint reads only w2 <= g
// words, all computed (absmax 0.0 in R16 proves the invariant).
__global__ __launch_bounds__(1024) void k_nms(
    const u64* __restrict__ cmask, const u64* __restrict__ validw,
    const float* __restrict__ cscore, const int* __restrict__ clabel,
    const float4* __restrict__ cbox, float* __restrict__ out)
{
    __shared__ __align__(16) u64 smask[16 * KPAD];   // 128 KB
    __shared__ u64 sk[16];
    __shared__ int pfx[17];
    __shared__ int slot[DETS];
    int b = blockIdx.x, t = threadIdx.x, lane = t & 63;

    // prefetch validw (wave 0 lanes 0..15, issued before staging)
    u64 vw_reg = 0;
    if (t < 16) vw_reg = validw[b * 16 + t];

    // ---- stage full image mask to LDS: 8192 float4 / 1024 threads ----
    {
        const float4* cm4 = (const float4*)(cmask + (size_t)b * 16 * KPAD);
        float4* sm4 = (float4*)smask;
        #pragma unroll
        for (int i = 0; i < 8; ++i) sm4[t + (i << 10)] = cm4[t + (i << 10)];
    }
    __syncthreads();

    // ---- NMS ballot fixpoint on wave 0, reading LDS ----
    if (t < 64) {
        u64 kept[16];
        #pragma unroll
        for (int g = 0; g < 16; ++g) {
            u64 vg = (u64)__shfl((long long)vw_reg, g);
            bool rem = false;
            #pragma unroll
            for (int w2 = 0; w2 < 16; ++w2)
                if (w2 < g)
                    rem |= (kept[w2] & smask[w2 * KPAD + g * 64 + lane]) != 0ULL;
            u64 cg = smask[g * KPAD + g * 64 + lane];
            bool myv = ((vg >> lane) & 1ULL) && !rem;
            u64 K = __ballot(myv);
            for (;;) {
                u64 K2 = __ballot(myv && ((K & cg) == 0ULL));
                if (K2 == K) break;
                K = K2;
            }
            kept[g] = K;                           // wave-uniform
        }
        if (lane == 0) {
            int run = 0;
            #pragma unroll
            for (int l = 0; l < 16; ++l) {
                sk[l] = kept[l]; pfx[l] = run; run += __popcll(kept[l]);
            }
            pfx[16] = run;
        }
    }
    __syncthreads();
    if (t < 16) {
        int r = pfx[t];
        u64 wv = sk[t];
        while (wv && r < DETS) {
            int bit = __builtin_ctzll(wv);
            slot[r] = t * 64 + bit;
            ++r;
            wv &= wv - 1;
        }
    }
    __syncthreads();
    int total = min(pfx[16], DETS);
    if (t < DETS) {
        int r = t;
        float4 bx = make_float4(0.f, 0.f, 0.f, 0.f);
        float s = 0.0f;
        int lb = -1;
        if (r < total) {
            int cdx = slot[r];
            bx = cbox[b * KPAD + cdx];
            s = cscore[b * KPAD + cdx];
            lb = clabel[b * KPAD + cdx];
        }
        float* ob = out + ((size_t)b * DETS + r) * 4;
        ob[0] = bx.x; ob[1] = bx.y; ob[2] = bx.z; ob[3] = bx.w;
        out[NIMG * DETS * 4 + b * DETS + r] = s;
        out[NIMG * DETS * 4 + NIMG * DETS + b * DETS + r] = (float)lb;
    }
}

// ============================================================ launch
extern "C" void kernel_launch(void* const* d_in, const int* in_sizes, int n_in,
                              void* d_out, int out_size, void* d_ws, size_t ws_size,
                              hipStream_t stream) {
    const float* logits = (const float*)d_in[0];
    const float* rel    = (const float*)d_in[1];
    const float* priors = (const float*)d_in[2];
    const int*   tsz    = (const int*)d_in[3];
    float* out = (float*)d_out;
    char* ws = (char*)d_ws;

    float* boxes  = (float*)(ws + OFF_BOXES);
    u32*   cnt    = (u32*)(ws + OFF_CNT);
    u32*   ghist  = (u32*)(ws + OFF_GHIST);
    float* cscore = (float*)(ws + OFF_CSCORE);
    int*   clabel = (int*)(ws + OFF_CLABEL);
    float4* cbox  = (float4*)(ws + OFF_CBOX);
    float4* coffs = (float4*)(ws + OFF_COFFS);
    u64*   validw = (u64*)(ws + OFF_VALIDW);
    u64*   cmask  = (u64*)(ws + OFF_MASK);
    u64*   cand   = (u64*)(ws + OFF_CAND);

    long long avail = ((long long)ws_size - (long long)OFF_CAND) / (NIMG * 8);
    int cap = (int)(avail < CAPMAX ? (avail > 0 ? avail : 1) : CAPMAX);
    cap &= ~1;                                    // even -> 16B-aligned per-image base

    hipMemsetAsync(cnt, 0, MEMSET_LEN, stream);   // cnt + ghist
    k_decode<<<NIMG * TILEB, 256, 0, stream>>>(logits, rel, priors, tsz,
                                               boxes, cand, cnt, ghist, cap);
    k_select<<<NIMG, 1024, 0, stream>>>(cand, cnt, ghist, boxes, cscore, clabel,
                                        cbox, coffs, validw, cap);
    k_iou<<<NIMG * IOUB, 1024, 0, stream>>>(coffs, cmask);
    k_nms<<<NIMG, 1024, 0, stream>>>(cmask, validw, cscore, clabel, cbox, out);
}

// Round 7
// 145.558 us; speedup vs baseline: 1.0278x; 1.0027x over previous
//
#include <hip/hip_runtime.h>
#include <math.h>

#pragma clang fp contract(off)

#define NIMG 16
#define NP   8732
#define NCLS 81
#define NFG  80
#define KTOP 1000
#define KPAD 1024
#define DETS 100
#define CAPMAX 166912          // >= 19*8732 (hard bound: <=19 softmax scores can exceed 0.05)
#define BASEBITS 0x3D000000u   // float bits of 0.03125, below 0.05 threshold; low 16 bits zero
#define CNT_STRIDE 64          // u32 units -> 256 B per image counter (own cacheline)
#define TILEB 137              // 64-prior tiles per image (137*64 >= 8732)
#define NB 640                 // hist bins: (sb-BASEBITS)>>16, clamp 639 (score<=1.0)
#define IOUB 9                 // ceil(136 triangular wave-words / 16 waves)

// ---- workspace layout (bytes) ----
#define OFF_BOXES  0u            // [NIMG][NP][4] f32 = 2,235,392
#define OFF_CNT    2235392u      // [NIMG] u32 @256B = 4,096
#define OFF_GHIST  2239488u      // [NIMG][640] u32 = 40,960
#define OFF_CSCORE 2280448u      // [NIMG][KPAD] f32
#define OFF_CLABEL 2345984u      // [NIMG][KPAD] i32
#define OFF_CBOX   2411520u      // [NIMG][KPAD] float4
#define OFF_COFFS  2673664u      // [NIMG][KPAD] float4
#define OFF_CAREA  2935808u      // [NIMG][KPAD] f32 (unused since R16; layout kept)
#define OFF_VALIDW 3001344u      // [NIMG][16] u64
#define OFF_MASK   3003392u      // [NIMG][16][KPAD] u64 column-major
#define OFF_CAND   5100544u      // [NIMG][cap] u64
#define MEMSET_LEN 45056u        // cnt + ghist (contiguous)

typedef unsigned long long u64;
typedef unsigned int u32;

#define AS_GLOBAL __attribute__((address_space(1)))
#define AS_LOCAL  __attribute__((address_space(3)))

// ============================================================ kernel 1
// 4 waves per 64-prior tile (verified R7-R10). Per-block LDS 640-bin score
// hist (R11), merged to global AFTER the emission loop (~14 nonzero bins/blk).
// R14: TILE-MAJOR grid (blockIdx = g*16 + b); per-wave atomic base on cnt[b]
// (order in cand[] is arbitrary; k_select sorts by full key).
__global__ __launch_bounds__(256, 6) void k_decode(
    const float* __restrict__ logits, const float* __restrict__ rel,
    const float* __restrict__ priors, const int* __restrict__ tsz,
    float* __restrict__ boxes_out, u64* __restrict__ cand,
    u32* __restrict__ cnt, u32* __restrict__ ghist, int cap)
{
#pragma clang fp contract(off)
    __shared__ __align__(16) float lx[64 * NCLS];   // 20,736 B flat [prior][class]
    __shared__ float pmx[4 * 64];
    __shared__ float psm[4 * 64];
    __shared__ u32 sok[64];
    __shared__ u32 lhist[NB];                        // 2,560 B
    int b  = blockIdx.x & 15;                        // image (XCD pin: b%8)
    int g  = blockIdx.x >> 4;                        // tile
    int p0 = g * 64;
    int t  = threadIdx.x;
    int lane = t & 63;
    int q = t >> 6;
    int npri = NP - p0; if (npri > 64) npri = 64;
    int words = npri * NCLS;

    // ---- async staging: chunks split across the 4 waves, one barrier ----
    const u32* s32 = (const u32*)(logits + ((size_t)b * NP + p0) * NCLS);
    u32* lxw = (u32*)lx;
    int full = words >> 8;                          // 1KB chunks (64 x 16 B)
    for (int k = q; k < full; k += 4)
        __builtin_amdgcn_global_load_lds(
            (AS_GLOBAL const u32*)(s32 + (k << 8) + (lane << 2)),
            (AS_LOCAL u32*)(lxw + (k << 8)), 16, 0, 0);
    int base = full << 8;
    int c4 = (words - base) >> 6;                   // 256B chunks (64 x 4 B)
    for (int k = q; k < c4; k += 4)
        __builtin_amdgcn_global_load_lds(
            (AS_GLOBAL const u32*)(s32 + base + (k << 6) + lane),
            (AS_LOCAL u32*)(lxw + base + (k << 6)), 4, 0, 0);
    int base2 = base + (c4 << 6);
    if (q == 0 && lane < words - base2) lxw[base2 + lane] = s32[base2 + lane];

    for (int i = t; i < NB; i += 256) lhist[i] = 0;  // overlaps DMA

    int p = p0 + lane;
    bool active = p < NP;

    // ---- box decode by wave 0 (independent of LDS; overlaps DMA) ----
    if (q == 0) {
        u32 ok = 0;
        if (active) {
            float4 pr = ((const float4*)priors)[p];
            float4 rl = ((const float4*)rel)[(size_t)b * NP + p];
            float W = (float)tsz[b * 2 + 1], H = (float)tsz[b * 2 + 0];
            float cx = pr.x + (rl.x * 0.1f) * pr.z;
            float cy = pr.y + (rl.y * 0.1f) * pr.w;
            float w_ = pr.z * expf(rl.z * 0.2f);
            float h_ = pr.w * expf(rl.w * 0.2f);
            float4 bx;
            bx.x = (cx - 0.5f * w_) * W; bx.y = (cy - 0.5f * h_) * H;
            bx.z = (cx + 0.5f * w_) * W; bx.w = (cy + 0.5f * h_) * H;
            ((float4*)boxes_out)[(size_t)b * NP + p] = bx;
            ok = ((bx.z - bx.x) >= 0.01f) && ((bx.w - bx.y) >= 0.01f);
        }
        sok[lane] = ok;
    }
    __syncthreads();                                 // #1: DMA drained + sok

    int tb = lane * NCLS;
    int nk = (q == 0) ? 21 : 20;                     // q==0 also owns c=80
    float x[21];
    #pragma unroll
    for (int k = 0; k < 21; ++k) {
        int c = q + 4 * k;
        x[k] = (k < nk) ? lx[tb + c] : -3.4e38f;
    }
    float pm = -3.4e38f;
    #pragma unroll
    for (int k = 0; k < 21; ++k) if (k < nk) pm = fmaxf(pm, x[k]);
    pmx[q * 64 + lane] = pm;
    __syncthreads();                                 // #2: partial max
    float m = fmaxf(fmaxf(pmx[lane], pmx[64 + lane]),
                    fmaxf(pmx[128 + lane], pmx[192 + lane]));

    float ps = 0.f;
    #pragma unroll
    for (int k = 0; k < 21; ++k) {
        if (k < nk) { x[k] = expf(x[k] - m); ps += x[k]; }
    }
    psm[q * 64 + lane] = ps;
    __syncthreads();                                 // #3: partial sum
    float s = (psm[lane] + psm[64 + lane]) + (psm[128 + lane] + psm[192 + lane]);

    float hi = 0.05000075f * s;
    float lo = 0.04999925f * s;
    u32 pass = 0, band = 0;
    u32 sizeok = sok[lane];
    if (active && sizeok) {
        #pragma unroll
        for (int k = 0; k < 21; ++k) {
            int c = q + 4 * k;
            if (k < nk && c >= 1) {
                bool pa = x[k] > hi;
                bool bd = (!pa) && (x[k] > lo);
                pass |= ((u32)pa) << k;
                band |= ((u32)bd) << k;
            }
        }
    }
    while (band) {
        int k = __builtin_ctz(band); band &= band - 1;
        int c = q + 4 * k;
        float e = expf(lx[tb + c] - m);
        if (e / s > 0.05f) pass |= 1u << k;
    }
    int cnt_t = __popc(pass);

    int pre = cnt_t;
    #pragma unroll
    for (int d = 1; d < 64; d <<= 1) {
        int o = __shfl_up(pre, d);
        if (lane >= d) pre += o;
    }
    // ---- per-wave base via one atomic (lane 63 holds wave total) ----
    u32 wbase = 0;
    if (lane == 63 && pre > 0)
        wbase = atomicAdd(cnt + b * CNT_STRIDE, (u32)pre);
    wbase = (u32)__shfl((int)wbase, 63);
    u32 pos = wbase + (u32)(pre - cnt_t);

    u64* cb = cand + (size_t)b * cap;
    u32 flatneg = 0xFFFFFFFFu - (u32)p * NFG;
    while (pass) {
        int k = __builtin_ctz(pass); pass &= pass - 1;
        int c = q + 4 * k;
        float e = expf(lx[tb + c] - m);
        float d = e / s;
        if ((int)pos < cap) {
            u32 sb = __float_as_uint(d);
            cb[pos] = ((u64)sb << 32) | (u64)(flatneg - (u32)(c - 1));
            u32 bin = (sb - BASEBITS) >> 16; if (bin > NB - 1) bin = NB - 1;
            atomicAdd(&lhist[bin], 1u);              // LDS, ~14 adds per block
        }
        ++pos;
    }
    __syncthreads();                                 // lhist complete
    u32* gh = ghist + b * NB;
    for (int i = t; i < NB; i += 256) {
        u32 v = lhist[i];
        if (v) atomicAdd(gh + i, v);                 // ~14 nonzero bins/block
    }
}

// ============================================================ suffix_find
// (rare fine-fallback path only): 8192-bin hierarchical suffix scan.
__device__ __forceinline__ void suffix_find(
    u32* hist, u32* wt, u32 K, int tid,
    volatile int* outI, volatile u32* outNext)
{
    int lane = tid & 63, w = tid >> 6;
    u32 v[8]; u32 tot = 0;
    #pragma unroll
    for (int k = 0; k < 8; ++k) { v[k] = hist[tid * 8 + k]; tot += v[k]; }
    u32 ws = tot;
    #pragma unroll
    for (int d = 1; d < 64; d <<= 1) {
        u32 o = __shfl_down(ws, d);
        if (lane + d < 64) ws += o;
    }
    if (lane == 0) wt[w] = ws;
    __syncthreads();
    u32 tail = 0;
    for (int w2 = w + 1; w2 < 16; ++w2) tail += wt[w2];
    u32 after = (ws - tot) + tail;
    u32 sufk[9];
    sufk[8] = after;
    #pragma unroll
    for (int k = 7; k >= 0; --k) sufk[k] = v[k] + sufk[k + 1];
    #pragma unroll
    for (int k = 0; k < 8; ++k) {
        if (sufk[k] >= K && sufk[k + 1] < K) {
            *outI = tid * 8 + k;
            *outNext = sufk[k + 1];
        }
    }
    __syncthreads();
}

// ============================================================ kernel 2
// FUSED select, ONE candidate pass (R11); pipelined float4 pass (R14);
// in-LDS fine refine -> 1024 sort common path (R15, -8us verified).
// R18: bitonic rounds k=2..64 fused into ONE register-resident segment —
// for k<=64 every exchange is intra-wave (j<=32 shfl) and each thread
// reads/writes only buf[t], so the 6 separate LDS round-trips + barriers
// were pure overhead. Exact bit-equivalence; applies to both sort paths.
__global__ __launch_bounds__(1024) void k_select(
    const u64* __restrict__ cand, const u32* __restrict__ cnt,
    const u32* __restrict__ ghist, const float* __restrict__ boxes,
    float* __restrict__ cscore, int* __restrict__ clabel,
    float4* __restrict__ cbox, float4* __restrict__ coffs,
    u64* __restrict__ validw, int cap)
{
#pragma clang fp contract(off)
    __shared__ u32 h[NB];
    __shared__ __align__(16) u32 fh[8192];  // fine hists; reused as u64 buf2
    __shared__ u32 wt[16];
    __shared__ u64 buf[2048];
    __shared__ float red16[16];
    __shared__ int sh_c, sh_i2, sh_f;
    __shared__ u32 sh_S, sh_next, sh_d, sh_m, sh_S2, sh_m2;
    int b = blockIdx.x, t = threadIdx.x, lane = t & 63;
    u32 n = min(cnt[b * CNT_STRIDE], (u32)cap);
    const u64* cb = cand + (size_t)b * cap;
    const float4* cb4 = (const float4*)cb;          // cap even -> 16B aligned

    // ---- issue chunk 0 of the candidate pass NOW (overlaps hist scan) ----
    float4 cur[4];
    #pragma unroll
    for (int e = 0; e < 4; ++e) {
        u32 p2 = (u32)(e << 10) + (u32)t;           // pair index (keys 2p2,2p2+1)
        cur[e] = make_float4(0.f, 0.f, 0.f, 0.f);
        if ((p2 << 1) < n) cur[e] = cb4[p2];
    }

    for (int i = t; i < NB; i += 1024) h[i] = ghist[b * NB + i];
    if (t == 0) { sh_c = -2; sh_i2 = -2; sh_S = 0; sh_next = 0; sh_m = 0; }
    __syncthreads();
    // ---- wave-0 suffix scan of 640 bins (10/lane) ----
    if (t < 64) {
        u32 v[10]; u32 tot = 0;
        #pragma unroll
        for (int k = 0; k < 10; ++k) { v[k] = h[t * 10 + k]; tot += v[k]; }
        u32 ws = tot;
        #pragma unroll
        for (int d = 1; d < 64; d <<= 1) {
            u32 o = (u32)__shfl_down((int)ws, d);
            if (t + d < 64) ws += o;
        }
        u32 suf[11];
        suf[10] = ws - tot;                          // suffix after my bins
        #pragma unroll
        for (int k = 9; k >= 0; --k) suf[k] = v[k] + suf[k + 1];
        #pragma unroll
        for (int k = 0; k < 10; ++k) {
            if (suf[k] >= (u32)KTOP && suf[k + 1] < (u32)KTOP) {
                sh_c = t * 10 + k; sh_S = suf[k]; sh_next = suf[k + 1];
            }
        }
    }
    __syncthreads();
    int c = sh_c;
    u32 T = 0;
    bool common_path = false;
    if (c >= 0) {
        u32 Tc = BASEBITS + ((u32)c << 16);
        if (sh_S <= 2048u) {
            T = Tc;                                  // common path, no pass
            common_path = true;
        } else {                                     // rare: gran-8 refine (1 pass)
            u32 nhi = sh_next;
            for (int i = t; i < 8192; i += 1024) fh[i] = 0;
            __syncthreads();
            for (u32 i = (u32)t; i < n; i += 1024) {
                u32 sb = (u32)(cb[i] >> 32);
                if ((sb & 0xFFFF0000u) == Tc)
                    atomicAdd(&fh[(sb >> 3) & 0x1FFFu], 1u);
            }
            __syncthreads();
            suffix_find(fh, wt, (u32)KTOP - nhi, t, &sh_i2, &sh_d);
            T = (sh_i2 >= 0) ? (Tc + ((u32)sh_i2 << 3)) : Tc;
        }
    }
    // ---- the ONE candidate pass: compact survivors (>= T) into LDS buf ----
    // pipelined: process cur (in regs), issue next chunk first.
    for (u32 bs0 = 0; bs0 < n; bs0 += 8192) {
        u32 bs1 = bs0 + 8192;
        float4 nxt[4];
        if (bs1 < n) {
            #pragma unroll
            for (int e = 0; e < 4; ++e) {
                u32 p2 = (bs1 >> 1) + (u32)(e << 10) + (u32)t;
                nxt[e] = make_float4(0.f, 0.f, 0.f, 0.f);
                if ((p2 << 1) < n) nxt[e] = cb4[p2];
            }
        } else {
            #pragma unroll
            for (int e = 0; e < 4; ++e) nxt[e] = make_float4(0.f, 0.f, 0.f, 0.f);
        }
        #pragma unroll
        for (int e = 0; e < 4; ++e) {
            u32 gk = bs0 + (((u32)(e << 10) + (u32)t) << 1);   // first key idx
            u64 k0 = ((u64)__float_as_uint(cur[e].y) << 32) | (u64)__float_as_uint(cur[e].x);
            u64 k1 = ((u64)__float_as_uint(cur[e].w) << 32) | (u64)__float_as_uint(cur[e].z);
            bool pick0 = (gk < n)     && ((u32)(k0 >> 32) >= T);
            bool pick1 = (gk + 1 < n) && ((u32)(k1 >> 32) >= T);
            u64 bal0 = __ballot(pick0);
            u32 wb = 0;
            if (lane == 0 && bal0) wb = atomicAdd(&sh_m, (u32)__popcll(bal0));
            wb = (u32)__shfl((int)wb, 0);
            if (pick0) {
                u32 pos = wb + (u32)__popcll(bal0 & ((1ULL << lane) - 1ULL));
                if (pos < 2048) buf[pos] = k0;
            }
            u64 bal1 = __ballot(pick1);
            u32 wb1 = 0;
            if (lane == 0 && bal1) wb1 = atomicAdd(&sh_m, (u32)__popcll(bal1));
            wb1 = (u32)__shfl((int)wb1, 0);
            if (pick1) {
                u32 pos = wb1 + (u32)__popcll(bal1 & ((1ULL << lane) - 1ULL));
                if (pos < 2048) buf[pos] = k1;
            }
        }
        #pragma unroll
        for (int e = 0; e < 4; ++e) cur[e] = nxt[e];
    }
    __syncthreads();
    u32 m = min(sh_m, 2048u);
    for (int i = t; i < 2048; i += 1024) if ((u32)i >= m) buf[i] = 0ULL;
    __syncthreads();

    // ---- R15: choose sort width; in-LDS refine to reach 1024 ----
    int sortn = 2048;
    if (m <= 1024u) {
        sortn = 1024;
    } else if (common_path) {
        // T == Tc. nhi = sh_next keys lie strictly above coarse bin c; we
        // need K2 = KTOP - nhi more from the boundary bin. Refine the
        // threshold at gran-32 using only LDS-resident survivors.
        u32 nhi = sh_next;
        u32 K2 = (u32)KTOP - nhi;                   // >= 1
        u32 cbin = (BASEBITS >> 16) + (u32)c;
        for (int i = t; i < 2048; i += 1024) fh[i] = 0;
        if (t == 0) { sh_f = -1; sh_S2 = 0; sh_m2 = 0; }
        __syncthreads();
        u64 a0 = buf[t], a1 = buf[t + 1024];
        u32 s0 = (u32)(a0 >> 32), s1 = (u32)(a1 >> 32);
        if ((s0 >> 16) == cbin) atomicAdd(&fh[(s0 >> 5) & 0x7FFu], 1u);
        if ((s1 >> 16) == cbin) atomicAdd(&fh[(s1 >> 5) & 0x7FFu], 1u);
        __syncthreads();
        // suffix scan of 2048 fine bins (2/thread), mirrors suffix_find
        {
            int l2 = t & 63, w2 = t >> 6;
            u32 v0b = fh[t * 2], v1b = fh[t * 2 + 1];
            u32 tot = v0b + v1b;
            u32 ws = tot;
            #pragma unroll
            for (int d = 1; d < 64; d <<= 1) {
                u32 o = (u32)__shfl_down((int)ws, d);
                if (l2 + d < 64) ws += o;
            }
            if (l2 == 0) wt[w2] = ws;
            __syncthreads();
            u32 tail = 0;
            for (int ww = w2 + 1; ww < 16; ++ww) tail += wt[ww];
            u32 after = (ws - tot) + tail;           // suffix after my 2 bins
            u32 suf1 = v1b + after;                  // suffix from bin 2t+1
            u32 suf0 = v0b + suf1;                   // suffix from bin 2t
            if (suf0 >= K2 && suf1 < K2)  { sh_f = t * 2;     sh_S2 = suf0; }
            if (suf1 >= K2 && after < K2) { sh_f = t * 2 + 1; sh_S2 = suf1; }
        }
        __syncthreads();
        if (sh_f >= 0 && nhi + sh_S2 <= 1024u) {
            u32 T2 = (cbin << 16) | ((u32)sh_f << 5);
            u64* buf2 = (u64*)fh;                    // 16 KB scratch (hist dead)
            bool p0 = (s0 >= T2);                    // zeros have s=0 < T2
            bool p1 = (s1 >= T2);
            u64 bal = __ballot(p0);
            u32 wb = 0;
            if (lane == 0 && bal) wb = atomicAdd(&sh_m2, (u32)__popcll(bal));
            wb = (u32)__shfl((int)wb, 0);
            if (p0) buf2[wb + (u32)__popcll(bal & ((1ULL << lane) - 1ULL))] = a0;
            bal = __ballot(p1);
            wb = 0;
            if (lane == 0 && bal) wb = atomicAdd(&sh_m2, (u32)__popcll(bal));
            wb = (u32)__shfl((int)wb, 0);
            if (p1) buf2[wb + (u32)__popcll(bal & ((1ULL << lane) - 1ULL))] = a1;
            __syncthreads();
            u32 m2 = sh_m2;                          // == nhi + sh_S2 <= 1024
            buf[t] = (t < (int)m2) ? buf2[t] : 0ULL; // buf[1024..2048) unused now
            sortn = 1024;
            __syncthreads();
        }
    }

    if (sortn == 1024) {
        // ---- hybrid bitonic sort, 1024 elems, full-key desc ----
        // R18: k=2..64 fused in-register (intra-wave only; own-slot only).
        {
            u64 v0 = buf[t];
            #pragma unroll
            for (int k = 2; k <= 64; k <<= 1) {
                bool up0 = (t & k) == 0;
                for (int j = k >> 1; j >= 1; j >>= 1) {
                    u64 o0 = __shfl_xor(v0, j);
                    bool lo0 = (t & j) == 0;
                    v0 = (lo0 == up0) ? (v0 > o0 ? v0 : o0) : (v0 < o0 ? v0 : o0);
                }
            }
            buf[t] = v0;
            __syncthreads();
        }
        for (int k = 128; k <= 1024; k <<= 1) {
            for (int j = k >> 1; j >= 64; j >>= 1) {
                int i = t;
                int ixj = i ^ j;
                if (ixj > i) {
                    u64 a = buf[i], bb = buf[ixj];
                    bool up = (i & k) == 0;
                    if (up ? (a < bb) : (a > bb)) { buf[i] = bb; buf[ixj] = a; }
                }
                __syncthreads();
            }
            u64 v0 = buf[t];
            bool up0 = (t & k) == 0;
            for (int j = 32; j >= 1; j >>= 1) {
                u64 o0 = __shfl_xor(v0, j);
                bool lo0 = (t & j) == 0;
                v0 = (lo0 == up0) ? (v0 > o0 ? v0 : o0) : (v0 < o0 ? v0 : o0);
            }
            buf[t] = v0;
            __syncthreads();
        }
    } else {
        // ---- hybrid bitonic sort, 2048 elems, full-key desc (fallback) ----
        // R18: k=2..64 fused in-register ((t+1024)&k == t&k for k<1024).
        {
            u64 v0 = buf[t], v1 = buf[t + 1024];
            #pragma unroll
            for (int k = 2; k <= 64; k <<= 1) {
                bool up0 = (t & k) == 0;
                for (int j = k >> 1; j >= 1; j >>= 1) {
                    u64 o0 = __shfl_xor(v0, j);
                    u64 o1 = __shfl_xor(v1, j);
                    bool lo0 = (t & j) == 0;
                    v0 = (lo0 == up0) ? (v0 > o0 ? v0 : o0) : (v0 < o0 ? v0 : o0);
                    v1 = (lo0 == up0) ? (v1 > o1 ? v1 : o1) : (v1 < o1 ? v1 : o1);
                }
            }
            buf[t] = v0; buf[t + 1024] = v1;
            __syncthreads();
        }
        for (int k = 128; k <= 2048; k <<= 1) {
            for (int j = k >> 1; j >= 64; j >>= 1) {
                #pragma unroll
                for (int e = 0; e < 2; ++e) {
                    int i = t + e * 1024;
                    int ixj = i ^ j;
                    if (ixj > i) {
                        u64 a = buf[i], bb = buf[ixj];
                        bool up = (i & k) == 0;
                        if (up ? (a < bb) : (a > bb)) { buf[i] = bb; buf[ixj] = a; }
                    }
                }
                __syncthreads();
            }
            u64 v0 = buf[t], v1 = buf[t + 1024];
            bool up0 = (t & k) == 0;
            bool up1 = ((t + 1024) & k) == 0;
            for (int j = 32; j >= 1; j >>= 1) {
                u64 o0 = __shfl_xor(v0, j);
                u64 o1 = __shfl_xor(v1, j);
                bool lo0 = (t & j) == 0;
                v0 = (lo0 == up0) ? (v0 > o0 ? v0 : o0) : (v0 < o0 ? v0 : o0);
                v1 = (lo0 == up1) ? (v1 > o1 ? v1 : o1) : (v1 < o1 ? v1 : o1);
            }
            buf[t] = v0; buf[t + 1024] = v1;
            __syncthreads();
        }
    }
    // ---- fused prep: t owns slot t of KPAD ----
    u64 key = (t < KTOP) ? buf[t] : 0ULL;
    float s = __uint_as_float((u32)(key >> 32));
    bool valid = s > 0.0f;
    u32 flat = valid ? (0xFFFFFFFFu - (u32)key) : 0u;
    int prior = (int)(flat / NFG);
    int cls = (int)(flat - (u32)prior * NFG) + 1;
    float4 bx = make_float4(0.f, 0.f, 0.f, 0.f);
    if (valid) bx = ((const float4*)boxes)[b * NP + prior];
    cscore[b * KPAD + t] = s;
    clabel[b * KPAD + t] = cls;
    cbox[b * KPAD + t] = bx;
    u64 vb = __ballot(valid);
    if (lane == 0) validw[b * 16 + (t >> 6)] = vb;
    float lm = valid ? fmaxf(fmaxf(bx.x, bx.y), fmaxf(bx.z, bx.w)) : 0.0f;
    lm = fmaxf(lm, 0.0f);
    #pragma unroll
    for (int d = 1; d < 64; d <<= 1) lm = fmaxf(lm, __shfl_xor(lm, d));
    if (lane == 0) red16[t >> 6] = lm;
    __syncthreads();
    float mc = red16[0];
    #pragma unroll
    for (int w = 1; w < 16; ++w) mc = fmaxf(mc, red16[w]);
    float off = (float)cls * (mc + 1.0f);
    float4 ob = valid ? make_float4(bx.x + off, bx.y + off, bx.z + off, bx.w + off)
                      : make_float4(0.f, 0.f, 0.f, 0.f);
    coffs[b * KPAD + t] = ob;
}

// ============================================================ kernel 3
// suppression bitmask, COLUMN-major: cmask[b][w][j] bit k = row (64w+k)
// suppresses column j. R17: FLAT TRIANGULAR grid — only the 136 live
// (tile,w) wave-words per image (w <= tile; lower triangle is identically
// zero and never read), packed 16 waves/block -> NIMG x 9 fully-active
// blocks. Every wave computes exactly one word. Area recomputed at staging
// (bitwise = old carea: same expr, same inputs, contract off).
__global__ __launch_bounds__(1024) void k_iou(
    const float4* __restrict__ coffs, u64* __restrict__ cmask)
{
#pragma clang fp contract(off)
    __shared__ float4 bs[KPAD];
    __shared__ float as_[KPAD];
    int b = blockIdx.x & 15, blk = blockIdx.x >> 4;
    int t = threadIdx.x;
    float4 v = coffs[b * KPAD + t];
    bs[t] = v;
    as_[t] = (v.z - v.x) * (v.w - v.y);
    __syncthreads();
    int f = blk * 16 + (t >> 6);                   // flat triangular word id
    if (f >= 136) return;                          // tail waves (no barrier after)
    int tile = 0;                                  // invert f = T(tile)+w
    #pragma unroll
    for (int x = 1; x < 16; ++x) if (x * (x + 1) / 2 <= f) tile = x;
    int w = f - tile * (tile + 1) / 2;             // w <= tile by construction
    int j = tile * 64 + (t & 63);                  // column (suppressee)
    float4 bj = bs[j];
    float aj = as_[j];
    int r0 = w * 64;
    u64 bits = 0;
    #pragma unroll 4
    for (int k = 0; k < 64; ++k) {
        int r = r0 + k;                            // wave-uniform row
        float4 br = bs[r];
        float ar = as_[r];
        float ltx = fmaxf(br.x, bj.x), lty = fmaxf(br.y, bj.y);
        float rbx = fminf(br.z, bj.z), rby = fminf(br.w, bj.w);
        float wx = fmaxf(rbx - ltx, 0.0f), wy = fmaxf(rby - lty, 0.0f);
        float inter = wx * wy;
        float denom = ((ar + aj) - inter) + 1e-9f;
        float iou = inter / denom;
        bool sup = (iou > 0.45f) && (j > r);
        bits |= ((u64)sup) << k;
    }
    cmask[((size_t)b * 16 + w) * KPAD + j] = bits;
}

// ============================================================ kernel 4
// NMS ballot fixpoint from LDS (R13); validw prefetch (R15); full 128 KB
// 8x-unrolled staging (R17 — the R16 triangular loop regressed). Lower-
// triangle words hold garbage (k_iou skips them) — harmless: the fixpoint
// reads only w2 <= g words, all computed.
__global__ __launch_bounds__(1024) void k_nms(
    const u64* __restrict__ cmask, const u64* __restrict__ validw,
    const float* __restrict__ cscore, const int* __restrict__ clabel,
    const float4* __restrict__ cbox, float* __restrict__ out)
{
    __shared__ __align__(16) u64 smask[16 * KPAD];   // 128 KB
    __shared__ u64 sk[16];
    __shared__ int pfx[17];
    __shared__ int slot[DETS];
    int b = blockIdx.x, t = threadIdx.x, lane = t & 63;

    // prefetch validw (wave 0 lanes 0..15, issued before staging)
    u64 vw_reg = 0;
    if (t < 16) vw_reg = validw[b * 16 + t];

    // ---- stage full image mask to LDS: 8192 float4 / 1024 threads ----
    {
        const float4* cm4 = (const float4*)(cmask + (size_t)b * 16 * KPAD);
        float4* sm4 = (float4*)smask;
        #pragma unroll
        for (int i = 0; i < 8; ++i) sm4[t + (i << 10)] = cm4[t + (i << 10)];
    }
    __syncthreads();

    // ---- NMS ballot fixpoint on wave 0, reading LDS ----
    if (t < 64) {
        u64 kept[16];
        #pragma unroll
        for (int g = 0; g < 16; ++g) {
            u64 vg = (u64)__shfl((long long)vw_reg, g);
            bool rem = false;
            #pragma unroll
            for (int w2 = 0; w2 < 16; ++w2)
                if (w2 < g)
                    rem |= (kept[w2] & smask[w2 * KPAD + g * 64 + lane]) != 0ULL;
            u64 cg = smask[g * KPAD + g * 64 + lane];
            bool myv = ((vg >> lane) & 1ULL) && !rem;
            u64 K = __ballot(myv);
            for (;;) {
                u64 K2 = __ballot(myv && ((K & cg) == 0ULL));
                if (K2 == K) break;
                K = K2;
            }
            kept[g] = K;                           // wave-uniform
        }
        if (lane == 0) {
            int run = 0;
            #pragma unroll
            for (int l = 0; l < 16; ++l) {
                sk[l] = kept[l]; pfx[l] = run; run += __popcll(kept[l]);
            }
            pfx[16] = run;
        }
    }
    __syncthreads();
    if (t < 16) {
        int r = pfx[t];
        u64 wv = sk[t];
        while (wv && r < DETS) {
            int bit = __builtin_ctzll(wv);
            slot[r] = t * 64 + bit;
            ++r;
            wv &= wv - 1;
        }
    }
    __syncthreads();
    int total = min(pfx[16], DETS);
    if (t < DETS) {
        int r = t;
        float4 bx = make_float4(0.f, 0.f, 0.f, 0.f);
        float s = 0.0f;
        int lb = -1;
        if (r < total) {
            int cdx = slot[r];
            bx = cbox[b * KPAD + cdx];
            s = cscore[b * KPAD + cdx];
            lb = clabel[b * KPAD + cdx];
        }
        float* ob = out + ((size_t)b * DETS + r) * 4;
        ob[0] = bx.x; ob[1] = bx.y; ob[2] = bx.z; ob[3] = bx.w;
        out[NIMG * DETS * 4 + b * DETS + r] = s;
        out[NIMG * DETS * 4 + NIMG * DETS + b * DETS + r] = (float)lb;
    }
}

// ============================================================ launch
extern "C" void kernel_launch(void* const* d_in, const int* in_sizes, int n_in,
                              void* d_out, int out_size, void* d_ws, size_t ws_size,
                              hipStream_t stream) {
    const float* logits = (const float*)d_in[0];
    const float* rel    = (const float*)d_in[1];
    const float* priors = (const float*)d_in[2];
    const int*   tsz    = (const int*)d_in[3];
    float* out = (float*)d_out;
    char* ws = (char*)d_ws;

    float* boxes  = (float*)(ws + OFF_BOXES);
    u32*   cnt    = (u32*)(ws + OFF_CNT);
    u32*   ghist  = (u32*)(ws + OFF_GHIST);
    float* cscore = (float*)(ws + OFF_CSCORE);
    int*   clabel = (int*)(ws + OFF_CLABEL);
    float4* cbox  = (float4*)(ws + OFF_CBOX);
    float4* coffs = (float4*)(ws + OFF_COFFS);
    u64*   validw = (u64*)(ws + OFF_VALIDW);
    u64*   cmask  = (u64*)(ws + OFF_MASK);
    u64*   cand   = (u64*)(ws + OFF_CAND);

    long long avail = ((long long)ws_size - (long long)OFF_CAND) / (NIMG * 8);
    int cap = (int)(avail < CAPMAX ? (avail > 0 ? avail : 1) : CAPMAX);
    cap &= ~1;                                    // even -> 16B-aligned per-image base

    hipMemsetAsync(cnt, 0, MEMSET_LEN, stream);   // cnt + ghist
    k_decode<<<NIMG * TILEB, 256, 0, stream>>>(logits, rel, priors, tsz,
                                               boxes, cand, cnt, ghist, cap);
    k_select<<<NIMG, 1024, 0, stream>>>(cand, cnt, ghist, boxes, cscore, clabel,
                                        cbox, coffs, validw, cap);
    k_iou<<<NIMG * IOUB, 1024, 0, stream>>>(coffs, cmask);
    k_nms<<<NIMG, 1024, 0, stream>>>(cmask, validw, cscore, clabel, cbox, out);
}